// Round 3
// baseline (362.900 us; speedup 1.0000x reference)
//
#include <hip/hip_runtime.h>
#include <math.h>

#define N_USERS 100000
#define N_ITEMS 200000
#define N_NODES 300000
#define EMB_DIM 64
#define N_EDGES 4000000
#define BATCH   8192
#define EMB_REG 2.5e-05f

#define BUCK_SH 9                       // 512 nodes per bucket
#define BN      512
#define NBUCK   586                     // ceil(300000/512)
#define BSLOT   7424                    // slots per bucket region (mean 6827 + 7 sigma)
#define EPB     8192                    // edges per block (partition kernel)
#define EPT     32                      // edges per thread
#define NBLK_A  489                     // ceil(N_EDGES/EPB)
#define NBLK_MARK (BATCH / 256)         // 32 mark blocks folded into kA
#define PACK_SH 19                      // t in bits[0:19), hrel in bits[19:28)
#define SCORE_BLOCKS (BATCH / 4)
#define SPMM_HALF 2344                  // blocks per spmm1 half (x64 nodes = 150,016)

typedef unsigned short u16;
typedef unsigned int   u32;
typedef unsigned char  u8;
typedef __attribute__((ext_vector_type(8))) u16 u16x8;
typedef __attribute__((ext_vector_type(2))) float f32x2;

__device__ __forceinline__ float bf2f(u16 x) {
    u32 u = ((u32)x) << 16;
    return __builtin_bit_cast(float, u);
}
__device__ __forceinline__ u16 f2bf(float f) {
    u32 u = __builtin_bit_cast(u32, f);
    return (u16)((u + 0x7FFFu + ((u >> 16) & 1u)) >> 16);
}

// ---------- phase A: partition edges into fixed bucket regions ----------
// LDS-staged, bucket-ordered scatter -> coalesced global flush.
// Tail blocks (blockIdx >= NBLK_A) do the scored-node marking and zero the
// fp8 dummy row of e0s8.
__global__ __launch_bounds__(256) void kA(const int* __restrict__ hh,
                                          const int* __restrict__ tt,
                                          int* __restrict__ bcur, int* __restrict__ gp,
                                          const int* __restrict__ users,
                                          const int* __restrict__ pos,
                                          const int* __restrict__ neg,
                                          u8* __restrict__ flags,
                                          u8* __restrict__ e0s8) {
    if (blockIdx.x >= NBLK_A) {        // ---- folded k_mark ----
        int i = (blockIdx.x - NBLK_A) * 256 + threadIdx.x;
        if (i < BATCH) {
            flags[users[i]] = 1;
            flags[N_USERS + pos[i]] = 1;
            flags[N_USERS + neg[i]] = 1;
        }
        if (blockIdx.x == NBLK_A && threadIdx.x < 16)   // zero dummy fp8 row (e0s8)
            ((int*)(e0s8 + (size_t)N_NODES * EMB_DIM))[threadIdx.x] = 0;
        return;
    }
    __shared__ int sh_cnt[NBUCK];
    __shared__ int sh_off[NBUCK];      // local exclusive offsets (block CSR)
    __shared__ int sh_base[NBUCK];     // global destination bases
    __shared__ int stage[EPB];         // bucket-ordered packed edges (32 kB)
    __shared__ u16 sbid[EPB];          // bucket id per staged slot (16 kB)
    int tid = threadIdx.x;
    for (int j = tid; j < NBUCK; j += 256) sh_cnt[j] = 0;
    __syncthreads();
    int cbase = blockIdx.x * EPB;
    int clen  = min(EPB, N_EDGES - cbase);
    int pk[EPT], bk[EPT];
    #pragma unroll
    for (int j = 0; j < EPT; ++j) {
        int i = j * 256 + tid;
        bk[j] = -1;
        if (i < clen) {
            int h = hh[cbase + i];
            int t = tt[cbase + i];
            int b = h >> BUCK_SH;
            bk[j] = b;
            pk[j] = ((h & (BN - 1)) << PACK_SH) | t;
            atomicAdd(&sh_cnt[b], 1);
        }
    }
    __syncthreads();
    if (tid < 64) {                    // exclusive scan over 586 bucket counts
        int lane = tid, carry = 0;
        for (int b0 = 0; b0 < NBUCK; b0 += 64) {
            int idx = b0 + lane;
            int v = (idx < NBUCK) ? sh_cnt[idx] : 0;
            int incl = v;
            #pragma unroll
            for (int d = 1; d < 64; d <<= 1) {
                int u = __shfl_up(incl, d, 64);
                if (lane >= d) incl += u;
            }
            if (idx < NBUCK) sh_off[idx] = carry + incl - v;
            carry += __shfl(incl, 63, 64);
        }
    }
    __syncthreads();
    for (int j = tid; j < NBUCK; j += 256) {
        int c = sh_cnt[j];
        sh_base[j] = j * BSLOT + (c ? atomicAdd(&bcur[j], c) : 0);
        sh_cnt[j] = 0;                 // reuse as local rank cursor
    }
    __syncthreads();
    #pragma unroll
    for (int j = 0; j < EPT; ++j) {
        if (bk[j] >= 0) {
            int r = atomicAdd(&sh_cnt[bk[j]], 1);
            int p = sh_off[bk[j]] + r;
            stage[p] = pk[j];
            sbid[p]  = (u16)bk[j];
        }
    }
    __syncthreads();
    for (int i = tid; i < clen; i += 256) {    // coalesced per-bucket runs
        int b = sbid[i];
        gp[sh_base[b] + i - sh_off[b]] = stage[i];
    }
}

// ---------- phase B: per-bucket exact CSR + sde[] + dinv[] + fp8 conversion ----------
__global__ __launch_bounds__(256) void kB(const int* __restrict__ bcur,
                                          int* __restrict__ gp,
                                          int2* __restrict__ sde, float* __restrict__ dinv,
                                          const float* __restrict__ uemb,
                                          const float* __restrict__ iemb,
                                          u8* __restrict__ e0s8) {
    __shared__ int   ncnt[BN];
    __shared__ int   noff[BN];
    __shared__ float sdv[BN];
    __shared__ int   slots[BSLOT];
    int b = blockIdx.x;
    int node0 = b << BUCK_SH;
    int nn = min(BN, N_NODES - node0);
    int base = b * BSLOT;
    int count = bcur[b];                         // relative cursor = exact count
    int tid = threadIdx.x;
    for (int j = tid; j < BN; j += 256) ncnt[j] = 0;
    __syncthreads();
    for (int i = tid; i < count; i += 256)
        atomicAdd(&ncnt[gp[base + i] >> PACK_SH], 1);
    __syncthreads();
    if (tid < 64) {                       // exclusive scan over 512 node counts
        int lane = tid, carry = 0;
        #pragma unroll
        for (int b0 = 0; b0 < BN; b0 += 64) {
            int idx = b0 + lane;
            int v = ncnt[idx];
            int incl = v;
            #pragma unroll
            for (int d = 1; d < 64; d <<= 1) {
                int u = __shfl_up(incl, d, 64);
                if (lane >= d) incl += u;
            }
            noff[idx] = carry + incl - v;
            carry += __shfl(incl, 63, 64);
        }
    }
    __syncthreads();
    for (int j = tid; j < nn; j += 256) {
        int c = ncnt[j];
        float dv = c > 0 ? rsqrtf((float)c) : 0.0f;
        sde[node0 + j]  = make_int2(base + noff[j], c);
        dinv[node0 + j] = dv;
        sdv[j] = dv;
    }
    __syncthreads();
    for (int j = tid; j < BN; j += 256) ncnt[j] = noff[j];   // ncnt = cursor
    __syncthreads();
    for (int i = tid; i < count; i += 256) {     // scatter t by node into LDS
        int p = gp[base + i];
        int r = atomicAdd(&ncnt[p >> PACK_SH], 1);
        slots[r] = p & ((1 << PACK_SH) - 1);
    }
    __syncthreads();
    for (int i = tid; i < count; i += 256)       // coalesced flush (aliases edges_t)
        gp[base + i] = slots[i];
    // fused: e0s8[v] = Q(dinv[v] * e0[v]) for this bucket's nodes
    for (int i = tid; i < nn * 8; i += 256) {
        int j = i >> 3;
        float sc = sdv[j];
        int gnode = node0 + j;
        size_t ebase = (size_t)gnode * EMB_DIM + (size_t)(i & 7) * 8;
        const size_t UELEMS = (size_t)N_USERS * EMB_DIM;
        const float* src = (ebase < UELEMS) ? uemb + ebase : iemb + (ebase - UELEMS);
        float4 a  = ((const float4*)src)[0];
        float4 c4 = ((const float4*)src)[1];
        u32 w0 = __builtin_amdgcn_cvt_pk_fp8_f32(sc * a.x,  sc * a.y,  0,  false);
        w0 = __builtin_amdgcn_cvt_pk_fp8_f32(sc * a.z,  sc * a.w,  w0, true);
        u32 w1 = __builtin_amdgcn_cvt_pk_fp8_f32(sc * c4.x, sc * c4.y, 0,  false);
        w1 = __builtin_amdgcn_cvt_pk_fp8_f32(sc * c4.z, sc * c4.w, w1, true);
        uint2 o; o.x = w0; o.y = w1;
        ((uint2*)e0s8)[(size_t)gnode * 8 + (i & 7)] = o;
    }
}

// ---------- layer-1 SpMM (fp8 pre-scaled rows): 16 nodes per wave ----------
// Split into two half-grids (node_base param) for profiler visibility.
// Dead lanes at node==N_NODES write the zero dummy row of emb1s8 (dst8),
// used by k_score's padded unrolled gather loop.
__global__ __launch_bounds__(256) void k_spmm1(const int2* __restrict__ sde,
                        const int* __restrict__ et,
                        const u8* __restrict__ src8,
                        const float* __restrict__ uemb, const float* __restrict__ iemb,
                        const u8* __restrict__ flags,
                        u16* __restrict__ dstb, u8* __restrict__ dst8,
                        int node_base) {
    int lane = threadIdx.x & 63;
    int g    = lane >> 2;          // node sub-index within wave (16 groups)
    int sl   = lane & 3;           // 16-B slot within the 64-B row
    int gb   = lane & 60;          // group base lane (for shfl)
    int node = node_base + blockIdx.x * 64 + ((threadIdx.x >> 6) << 4) + g;
    bool alive = node < N_NODES;
    int2 se = alive ? sde[node] : make_int2(0, 0);
    int s = se.x, ne = se.y;
    float dh = ne > 0 ? rsqrtf((float)ne) : 0.0f;   // == dinv[node], bit-identical
    float acc[16];
    #pragma unroll
    for (int k = 0; k < 16; ++k) acc[k] = 0.f;
    int nb = (ne + 3) & ~3;        // per-group bound -> divergent early exit
    for (int j0 = 0; j0 < nb; j0 += 4) {
        int idx = j0 + sl;
        int ets = (idx < ne) ? et[s + idx] : N_NODES;  // pad -> zero row
        #pragma unroll
        for (int jj = 0; jj < 4; ++jj) {
            int t = __shfl(ets, gb | jj, 64);          // src lane in own group
            uint4 d8 = ((const uint4*)(src8 + (size_t)t * EMB_DIM))[sl];
            f32x2 p;
            p = __builtin_amdgcn_cvt_pk_f32_fp8(d8.x, false); acc[0]  += p.x; acc[1]  += p.y;
            p = __builtin_amdgcn_cvt_pk_f32_fp8(d8.x, true);  acc[2]  += p.x; acc[3]  += p.y;
            p = __builtin_amdgcn_cvt_pk_f32_fp8(d8.y, false); acc[4]  += p.x; acc[5]  += p.y;
            p = __builtin_amdgcn_cvt_pk_f32_fp8(d8.y, true);  acc[6]  += p.x; acc[7]  += p.y;
            p = __builtin_amdgcn_cvt_pk_f32_fp8(d8.z, false); acc[8]  += p.x; acc[9]  += p.y;
            p = __builtin_amdgcn_cvt_pk_f32_fp8(d8.z, true);  acc[10] += p.x; acc[11] += p.y;
            p = __builtin_amdgcn_cvt_pk_f32_fp8(d8.w, false); acc[12] += p.x; acc[13] += p.y;
            p = __builtin_amdgcn_cvt_pk_f32_fp8(d8.w, true);  acc[14] += p.x; acc[15] += p.y;
        }
    }
    if (!alive) {
        if (node == N_NODES) {      // zero dummy row for k_score's padded loop
            uint4 z; z.x = 0; z.y = 0; z.z = 0; z.w = 0;
            ((uint4*)(dst8 + (size_t)N_NODES * EMB_DIM))[sl] = z;
        }
        return;
    }
    // epilogue: all 64 lanes active; wave covers 16 consecutive nodes
    const float* srow = (node < N_USERS)
        ? uemb + (size_t)node * EMB_DIM
        : iemb + (size_t)(node - N_USERS) * EMB_DIM;
    float4 a0 = ((const float4*)srow)[sl * 4 + 0];
    float4 a1 = ((const float4*)srow)[sl * 4 + 1];
    float4 a2 = ((const float4*)srow)[sl * 4 + 2];
    float4 a3 = ((const float4*)srow)[sl * 4 + 3];
    float v[16];
    v[0]  = dh * acc[0]  + a0.x; v[1]  = dh * acc[1]  + a0.y;
    v[2]  = dh * acc[2]  + a0.z; v[3]  = dh * acc[3]  + a0.w;
    v[4]  = dh * acc[4]  + a1.x; v[5]  = dh * acc[5]  + a1.y;
    v[6]  = dh * acc[6]  + a1.z; v[7]  = dh * acc[7]  + a1.w;
    v[8]  = dh * acc[8]  + a2.x; v[9]  = dh * acc[9]  + a2.y;
    v[10] = dh * acc[10] + a2.z; v[11] = dh * acc[11] + a2.w;
    v[12] = dh * acc[12] + a3.x; v[13] = dh * acc[13] + a3.y;
    v[14] = dh * acc[14] + a3.z; v[15] = dh * acc[15] + a3.w;
    uint4 ow;
    u32 w;
    w = __builtin_amdgcn_cvt_pk_fp8_f32(dh * v[0],  dh * v[1],  0, false);
    w = __builtin_amdgcn_cvt_pk_fp8_f32(dh * v[2],  dh * v[3],  w, true);  ow.x = w;
    w = __builtin_amdgcn_cvt_pk_fp8_f32(dh * v[4],  dh * v[5],  0, false);
    w = __builtin_amdgcn_cvt_pk_fp8_f32(dh * v[6],  dh * v[7],  w, true);  ow.y = w;
    w = __builtin_amdgcn_cvt_pk_fp8_f32(dh * v[8],  dh * v[9],  0, false);
    w = __builtin_amdgcn_cvt_pk_fp8_f32(dh * v[10], dh * v[11], w, true);  ow.z = w;
    w = __builtin_amdgcn_cvt_pk_fp8_f32(dh * v[12], dh * v[13], 0, false);
    w = __builtin_amdgcn_cvt_pk_fp8_f32(dh * v[14], dh * v[15], w, true);  ow.w = w;
    ((uint4*)(dst8 + (size_t)node * EMB_DIM))[sl] = ow;   // 1 kB/wave, coalesced
    if (flags[node]) {
        u16x8 o0, o1;
        o0.s0 = f2bf(v[0]);  o0.s1 = f2bf(v[1]);  o0.s2 = f2bf(v[2]);  o0.s3 = f2bf(v[3]);
        o0.s4 = f2bf(v[4]);  o0.s5 = f2bf(v[5]);  o0.s6 = f2bf(v[6]);  o0.s7 = f2bf(v[7]);
        o1.s0 = f2bf(v[8]);  o1.s1 = f2bf(v[9]);  o1.s2 = f2bf(v[10]); o1.s3 = f2bf(v[11]);
        o1.s4 = f2bf(v[12]); o1.s5 = f2bf(v[13]); o1.s6 = f2bf(v[14]); o1.s7 = f2bf(v[15]);
        ((u16x8*)(dstb + (size_t)node * EMB_DIM))[sl * 2]     = o0;
        ((u16x8*)(dstb + (size_t)node * EMB_DIM))[sl * 2 + 1] = o1;
    }
}

// ---------- scoring + fused final reduction (last-block-done) ----------
// Inner gather loop unrolled x4 with N_NODES zero-row padding.
// Each block also clears its slice of flags for the next iteration.
__global__ void k_score(const int* __restrict__ users, const int* __restrict__ pos,
                        const int* __restrict__ neg,
                        const float* __restrict__ uemb, const float* __restrict__ iemb,
                        const u16* __restrict__ emb1b, const u8* __restrict__ emb1s8,
                        const int2* __restrict__ sde, const int* __restrict__ et,
                        const float* __restrict__ dinv,
                        float* __restrict__ pmf, float* __restrict__ psq,
                        u8* __restrict__ flags, int* __restrict__ cnt,
                        float* __restrict__ out) {
    __shared__ float smf[4], ssq[4];
    __shared__ int swin;
    int gid = blockIdx.x * blockDim.x + threadIdx.x;
    int b = gid >> 6;
    int d = gid & 63;
    int w = threadIdx.x >> 6;
    int u  = users[b];
    int pi = pos[b];
    int ni = neg[b];
    int nodes[3];
    nodes[0] = u; nodes[1] = N_USERS + pi; nodes[2] = N_USERS + ni;
    float pre[3];
    pre[0] = uemb[(size_t)u * EMB_DIM + d];
    pre[1] = iemb[(size_t)pi * EMB_DIM + d];
    pre[2] = iemb[(size_t)ni * EMB_DIM + d];
    int s0[3], ne[3], ets[3];
    float dv[3];
    #pragma unroll
    for (int k = 0; k < 3; ++k) {
        int v = nodes[k];
        int2 se = sde[v];
        s0[k] = se.x; ne[k] = se.y;
        dv[k] = dinv[v];
        ets[k] = (d < ne[k]) ? et[se.x + d] : N_NODES;   // pad -> zero row
    }
    float a[3];
    #pragma unroll
    for (int k = 0; k < 3; ++k) {
        float ac = 0.f;
        int lim = ne[k] < 64 ? ne[k] : 64;
        int lim4 = (lim + 3) & ~3;
        for (int j = 0; j < lim4; j += 4) {           // 4 gathers in flight
            int t0 = __shfl(ets[k], j,     64);
            int t1 = __shfl(ets[k], j + 1, 64);
            int t2 = __shfl(ets[k], j + 2, 64);
            int t3 = __shfl(ets[k], j + 3, 64);
            u32 b0 = emb1s8[(size_t)t0 * EMB_DIM + d];
            u32 b1 = emb1s8[(size_t)t1 * EMB_DIM + d];
            u32 b2 = emb1s8[(size_t)t2 * EMB_DIM + d];
            u32 b3 = emb1s8[(size_t)t3 * EMB_DIM + d];
            ac += __builtin_amdgcn_cvt_f32_fp8(b0, 0);
            ac += __builtin_amdgcn_cvt_f32_fp8(b1, 0);
            ac += __builtin_amdgcn_cvt_f32_fp8(b2, 0);
            ac += __builtin_amdgcn_cvt_f32_fp8(b3, 0);
        }
        for (int i = s0[k] + 64; i < s0[k] + ne[k]; ++i) {   // rare deg>64 tail
            int t = et[i];
            u32 byte = emb1s8[(size_t)t * EMB_DIM + d];
            ac += __builtin_amdgcn_cvt_f32_fp8(byte, 0);
        }
        a[k] = pre[k] + 2.0f * bf2f(emb1b[(size_t)nodes[k] * EMB_DIM + d]) + dv[k] * ac;
    }
    float ps = a[0] * a[1];
    float ns = a[0] * a[2];
    float sq = pre[0] * pre[0] + pre[1] * pre[1] + pre[2] * pre[2];
    #pragma unroll
    for (int off2 = 32; off2 > 0; off2 >>= 1) {
        ps += __shfl_down(ps, off2, 64);
        ns += __shfl_down(ns, off2, 64);
        sq += __shfl_down(sq, off2, 64);
    }
    if (d == 0) {
        float x  = ns - ps;
        smf[w] = fmaxf(x, 0.0f) + log1pf(expf(-fabsf(x)));
        ssq[w] = sq;
    }
    // clear this block's slice of flags for the next iteration (37 ints/block)
    {
        int* fi = (int*)flags;
        int idx = blockIdx.x * 37 + threadIdx.x;
        if (threadIdx.x < 37 && idx < (N_NODES + 3) / 4 + 8)
            fi[idx] = 0;
    }
    __syncthreads();
    if (threadIdx.x == 0) {
        pmf[blockIdx.x] = smf[0] + smf[1] + smf[2] + smf[3];
        psq[blockIdx.x] = ssq[0] + ssq[1] + ssq[2] + ssq[3];
        __threadfence();
        int old = __hip_atomic_fetch_add(cnt, 1, __ATOMIC_ACQ_REL,
                                         __HIP_MEMORY_SCOPE_AGENT);
        swin = (old == SCORE_BLOCKS - 1) ? 1 : 0;
    }
    __syncthreads();
    if (swin) {                         // deterministic final reduction
        __threadfence();
        int tid = threadIdx.x;
        float mf = 0.f, sq2 = 0.f;
        #pragma unroll
        for (int i = 0; i < SCORE_BLOCKS / 256; ++i) {
            u32 um = __hip_atomic_load((const u32*)&pmf[tid + i * 256],
                                       __ATOMIC_RELAXED, __HIP_MEMORY_SCOPE_AGENT);
            u32 us = __hip_atomic_load((const u32*)&psq[tid + i * 256],
                                       __ATOMIC_RELAXED, __HIP_MEMORY_SCOPE_AGENT);
            mf += __builtin_bit_cast(float, um);
            sq2 += __builtin_bit_cast(float, us);
        }
        #pragma unroll
        for (int off2 = 32; off2 > 0; off2 >>= 1) {
            mf += __shfl_down(mf, off2, 64);
            sq2 += __shfl_down(sq2, off2, 64);
        }
        if ((tid & 63) == 0) { smf[tid >> 6] = mf; ssq[tid >> 6] = sq2; }
        __syncthreads();
        if (tid == 0) {
            out[0] = (smf[0] + smf[1] + smf[2] + smf[3]) * (1.0f / BATCH);
            out[1] = EMB_REG * (ssq[0] + ssq[1] + ssq[2] + ssq[3]);
        }
    }
}

extern "C" void kernel_launch(void* const* d_in, const int* in_sizes, int n_in,
                              void* d_out, int out_size, void* d_ws, size_t ws_size,
                              hipStream_t stream) {
    const float* uemb  = (const float*)d_in[0];
    const float* iemb  = (const float*)d_in[1];
    const int*   all_h = (const int*)d_in[2];
    const int*   all_t = (const int*)d_in[3];
    const int*   users = (const int*)d_in[4];
    const int*   pos   = (const int*)d_in[5];
    const int*   neg   = (const int*)d_in[6];
    float* out = (float*)d_out;

    // workspace layout (int units)
    int*   ws     = (int*)d_ws;
    float* dinv   = (float*)ws;                  // 300,032 floats
    int2*  sde    = (int2*)(ws + 300032);        // 600,064 ints
    u8*    flags  = (u8*)(ws + 900096);          // 75,008 ints (300,032 B)
    int*   bcur   = ws + 975104;                 // 1024 ints (zero-init, relative)
    float* pmf    = (float*)(ws + 976128);       // 2048
    float* psq    = (float*)(ws + 978176);       // 2048
    int*   gp     = ws + 980224;                 // 586*7424 = 4,350,464 ints
    u8*    e0s8   = (u8*)(ws + 5330688);         // 300,001 rows x 64 B (incl dummy)
    u8*    emb1s8 = (u8*)(ws + 10130944);        // 300,001 rows x 64 B (incl dummy)
    u16*   emb1b  = (u16*)(ws + 14930944);       // 9.6M ints (38.4 MB)
    int*   cnt    = bcur + 640;                  // inside zeroed bcur region

    // zero bcur cursors + completion counter only (flags cleared by k_score)
    hipMemsetAsync(bcur, 0, 4096, stream);

    // partition (+ folded mark + e0s8 dummy-row zero)
    kA <<<NBLK_A + NBLK_MARK, 256, 0, stream>>>(all_h, all_t, bcur, gp,
                                                users, pos, neg, flags, e0s8);
    kB <<<NBUCK, 256, 0, stream>>>(bcur, gp, sde, dinv, uemb, iemb, e0s8);

    // layer 1 (two halves for profiler visibility of the other kernels)
    k_spmm1<<<SPMM_HALF, 256, 0, stream>>>(sde, gp, e0s8, uemb, iemb,
                                           flags, emb1b, emb1s8, 0);
    k_spmm1<<<SPMM_HALF, 256, 0, stream>>>(sde, gp, e0s8, uemb, iemb,
                                           flags, emb1b, emb1s8, SPMM_HALF * 64);

    // scoring + fused final reduction + flags clear
    k_score<<<SCORE_BLOCKS, 256, 0, stream>>>(users, pos, neg, uemb, iemb,
                                              emb1b, emb1s8, sde, gp, dinv,
                                              pmf, psq, flags, cnt, out);
}

// Round 5
// 284.323 us; speedup vs baseline: 1.2764x; 1.2764x over previous
//
#include <hip/hip_runtime.h>
#include <math.h>

#define N_USERS 100000
#define N_ITEMS 200000
#define N_NODES 300000
#define EMB_DIM 64
#define N_EDGES 4000000
#define BATCH   8192
#define EMB_REG 2.5e-05f

#define BUCK_SH 9                       // 512 nodes per bucket
#define BN      512
#define NBUCK   586                     // ceil(300000/512)
#define BSLOT   7424                    // slots per bucket region (mean 6827 + 7 sigma)
#define EPB     8192                    // edges per block (partition kernel)
#define EPT     32                      // edges per thread
#define NBLK_A  489                     // ceil(N_EDGES/EPB)
#define NBLK_MARK (BATCH / 256)         // 32 mark blocks folded into kA
#define PACK_SH 19                      // t in bits[0:19), hrel in bits[19:28)
#define SCORE_BLOCKS (BATCH / 4)

typedef unsigned short u16;
typedef unsigned int   u32;
typedef unsigned char  u8;
typedef __attribute__((ext_vector_type(8))) u16 u16x8;
typedef __attribute__((ext_vector_type(2))) float f32x2;

__device__ __forceinline__ float bf2f(u16 x) {
    u32 u = ((u32)x) << 16;
    return __builtin_bit_cast(float, u);
}
__device__ __forceinline__ u16 f2bf(float f) {
    u32 u = __builtin_bit_cast(u32, f);
    return (u16)((u + 0x7FFFu + ((u >> 16) & 1u)) >> 16);
}

// ---------- phase A: partition edges into fixed bucket regions ----------
// LDS-staged, bucket-ordered scatter -> coalesced global flush.
// Tail blocks (blockIdx >= NBLK_A) do the scored-node marking and zero the
// fp8 dummy row of e0s8.
__global__ __launch_bounds__(256) void kA(const int* __restrict__ hh,
                                          const int* __restrict__ tt,
                                          int* __restrict__ bcur, int* __restrict__ gp,
                                          const int* __restrict__ users,
                                          const int* __restrict__ pos,
                                          const int* __restrict__ neg,
                                          u8* __restrict__ flags,
                                          u8* __restrict__ e0s8) {
    if (blockIdx.x >= NBLK_A) {        // ---- folded k_mark ----
        int i = (blockIdx.x - NBLK_A) * 256 + threadIdx.x;
        if (i < BATCH) {
            flags[users[i]] = 1;
            flags[N_USERS + pos[i]] = 1;
            flags[N_USERS + neg[i]] = 1;
        }
        if (blockIdx.x == NBLK_A && threadIdx.x < 16)   // zero dummy fp8 row (e0s8)
            ((int*)(e0s8 + (size_t)N_NODES * EMB_DIM))[threadIdx.x] = 0;
        return;
    }
    __shared__ int sh_cnt[NBUCK];
    __shared__ int sh_off[NBUCK];      // local exclusive offsets (block CSR)
    __shared__ int sh_base[NBUCK];     // global destination bases
    __shared__ int stage[EPB];         // bucket-ordered packed edges (32 kB)
    __shared__ u16 sbid[EPB];          // bucket id per staged slot (16 kB)
    int tid = threadIdx.x;
    for (int j = tid; j < NBUCK; j += 256) sh_cnt[j] = 0;
    __syncthreads();
    int cbase = blockIdx.x * EPB;
    int clen  = min(EPB, N_EDGES - cbase);
    int pk[EPT], bk[EPT];
    #pragma unroll
    for (int j = 0; j < EPT; ++j) {
        int i = j * 256 + tid;
        bk[j] = -1;
        if (i < clen) {
            int h = hh[cbase + i];
            int t = tt[cbase + i];
            int b = h >> BUCK_SH;
            bk[j] = b;
            pk[j] = ((h & (BN - 1)) << PACK_SH) | t;
            atomicAdd(&sh_cnt[b], 1);
        }
    }
    __syncthreads();
    if (tid < 64) {                    // exclusive scan over 586 bucket counts
        int lane = tid, carry = 0;
        for (int b0 = 0; b0 < NBUCK; b0 += 64) {
            int idx = b0 + lane;
            int v = (idx < NBUCK) ? sh_cnt[idx] : 0;
            int incl = v;
            #pragma unroll
            for (int d = 1; d < 64; d <<= 1) {
                int u = __shfl_up(incl, d, 64);
                if (lane >= d) incl += u;
            }
            if (idx < NBUCK) sh_off[idx] = carry + incl - v;
            carry += __shfl(incl, 63, 64);
        }
    }
    __syncthreads();
    for (int j = tid; j < NBUCK; j += 256) {
        int c = sh_cnt[j];
        sh_base[j] = j * BSLOT + (c ? atomicAdd(&bcur[j], c) : 0);
        sh_cnt[j] = 0;                 // reuse as local rank cursor
    }
    __syncthreads();
    #pragma unroll
    for (int j = 0; j < EPT; ++j) {
        if (bk[j] >= 0) {
            int r = atomicAdd(&sh_cnt[bk[j]], 1);
            int p = sh_off[bk[j]] + r;
            stage[p] = pk[j];
            sbid[p]  = (u16)bk[j];
        }
    }
    __syncthreads();
    for (int i = tid; i < clen; i += 256) {    // coalesced per-bucket runs
        int b = sbid[i];
        gp[sh_base[b] + i - sh_off[b]] = stage[i];
    }
}

// ---------- phase B: per-bucket exact CSR + sde[] + dinv[] + fp8 conversion ----------
__global__ __launch_bounds__(256) void kB(const int* __restrict__ bcur,
                                          int* __restrict__ gp,
                                          int2* __restrict__ sde, float* __restrict__ dinv,
                                          const float* __restrict__ uemb,
                                          const float* __restrict__ iemb,
                                          u8* __restrict__ e0s8) {
    __shared__ int   ncnt[BN];
    __shared__ int   noff[BN];
    __shared__ float sdv[BN];
    __shared__ int   slots[BSLOT];
    int b = blockIdx.x;
    int node0 = b << BUCK_SH;
    int nn = min(BN, N_NODES - node0);
    int base = b * BSLOT;
    int count = bcur[b];                         // relative cursor = exact count
    int tid = threadIdx.x;
    for (int j = tid; j < BN; j += 256) ncnt[j] = 0;
    __syncthreads();
    for (int i = tid; i < count; i += 256)
        atomicAdd(&ncnt[gp[base + i] >> PACK_SH], 1);
    __syncthreads();
    if (tid < 64) {                       // exclusive scan over 512 node counts
        int lane = tid, carry = 0;
        #pragma unroll
        for (int b0 = 0; b0 < BN; b0 += 64) {
            int idx = b0 + lane;
            int v = ncnt[idx];
            int incl = v;
            #pragma unroll
            for (int d = 1; d < 64; d <<= 1) {
                int u = __shfl_up(incl, d, 64);
                if (lane >= d) incl += u;
            }
            noff[idx] = carry + incl - v;
            carry += __shfl(incl, 63, 64);
        }
    }
    __syncthreads();
    for (int j = tid; j < nn; j += 256) {
        int c = ncnt[j];
        float dv = c > 0 ? rsqrtf((float)c) : 0.0f;
        sde[node0 + j]  = make_int2(base + noff[j], c);
        dinv[node0 + j] = dv;
        sdv[j] = dv;
    }
    __syncthreads();
    for (int j = tid; j < BN; j += 256) ncnt[j] = noff[j];   // ncnt = cursor
    __syncthreads();
    for (int i = tid; i < count; i += 256) {     // scatter t by node into LDS
        int p = gp[base + i];
        int r = atomicAdd(&ncnt[p >> PACK_SH], 1);
        slots[r] = p & ((1 << PACK_SH) - 1);
    }
    __syncthreads();
    for (int i = tid; i < count; i += 256)       // coalesced flush (aliases edges_t)
        gp[base + i] = slots[i];
    // fused: e0s8[v] = Q(dinv[v] * e0[v]) for this bucket's nodes
    for (int i = tid; i < nn * 8; i += 256) {
        int j = i >> 3;
        float sc = sdv[j];
        int gnode = node0 + j;
        size_t ebase = (size_t)gnode * EMB_DIM + (size_t)(i & 7) * 8;
        const size_t UELEMS = (size_t)N_USERS * EMB_DIM;
        const float* src = (ebase < UELEMS) ? uemb + ebase : iemb + (ebase - UELEMS);
        float4 a  = ((const float4*)src)[0];
        float4 c4 = ((const float4*)src)[1];
        u32 w0 = __builtin_amdgcn_cvt_pk_fp8_f32(sc * a.x,  sc * a.y,  0,  false);
        w0 = __builtin_amdgcn_cvt_pk_fp8_f32(sc * a.z,  sc * a.w,  w0, true);
        u32 w1 = __builtin_amdgcn_cvt_pk_fp8_f32(sc * c4.x, sc * c4.y, 0,  false);
        w1 = __builtin_amdgcn_cvt_pk_fp8_f32(sc * c4.z, sc * c4.w, w1, true);
        uint2 o; o.x = w0; o.y = w1;
        ((uint2*)e0s8)[(size_t)gnode * 8 + (i & 7)] = o;
    }
}

// ---------- layer-1 SpMM (fp8 pre-scaled rows): 16 nodes per wave ----------
// Dead lanes at node==N_NODES write the zero dummy row of emb1s8 (dst8),
// used by k_score's interleaved padded gather loop.
__global__ __launch_bounds__(256) void k_spmm1(const int2* __restrict__ sde,
                        const int* __restrict__ et,
                        const u8* __restrict__ src8,
                        const float* __restrict__ uemb, const float* __restrict__ iemb,
                        const u8* __restrict__ flags,
                        u16* __restrict__ dstb, u8* __restrict__ dst8) {
    int lane = threadIdx.x & 63;
    int g    = lane >> 2;          // node sub-index within wave (16 groups)
    int sl   = lane & 3;           // 16-B slot within the 64-B row
    int gb   = lane & 60;          // group base lane (for shfl)
    int node = blockIdx.x * 64 + ((threadIdx.x >> 6) << 4) + g;
    bool alive = node < N_NODES;
    int2 se = alive ? sde[node] : make_int2(0, 0);
    int s = se.x, ne = se.y;
    float dh = ne > 0 ? rsqrtf((float)ne) : 0.0f;   // == dinv[node], bit-identical
    float acc[16];
    #pragma unroll
    for (int k = 0; k < 16; ++k) acc[k] = 0.f;
    int nb = (ne + 3) & ~3;        // per-group bound -> divergent early exit
    for (int j0 = 0; j0 < nb; j0 += 4) {
        int idx = j0 + sl;
        int ets = (idx < ne) ? et[s + idx] : N_NODES;  // pad -> zero row
        #pragma unroll
        for (int jj = 0; jj < 4; ++jj) {
            int t = __shfl(ets, gb | jj, 64);          // src lane in own group
            uint4 d8 = ((const uint4*)(src8 + (size_t)t * EMB_DIM))[sl];
            f32x2 p;
            p = __builtin_amdgcn_cvt_pk_f32_fp8(d8.x, false); acc[0]  += p.x; acc[1]  += p.y;
            p = __builtin_amdgcn_cvt_pk_f32_fp8(d8.x, true);  acc[2]  += p.x; acc[3]  += p.y;
            p = __builtin_amdgcn_cvt_pk_f32_fp8(d8.y, false); acc[4]  += p.x; acc[5]  += p.y;
            p = __builtin_amdgcn_cvt_pk_f32_fp8(d8.y, true);  acc[6]  += p.x; acc[7]  += p.y;
            p = __builtin_amdgcn_cvt_pk_f32_fp8(d8.z, false); acc[8]  += p.x; acc[9]  += p.y;
            p = __builtin_amdgcn_cvt_pk_f32_fp8(d8.z, true);  acc[10] += p.x; acc[11] += p.y;
            p = __builtin_amdgcn_cvt_pk_f32_fp8(d8.w, false); acc[12] += p.x; acc[13] += p.y;
            p = __builtin_amdgcn_cvt_pk_f32_fp8(d8.w, true);  acc[14] += p.x; acc[15] += p.y;
        }
    }
    if (!alive) {
        if (node == N_NODES) {      // zero dummy row for k_score's padded loop
            uint4 z; z.x = 0; z.y = 0; z.z = 0; z.w = 0;
            ((uint4*)(dst8 + (size_t)N_NODES * EMB_DIM))[sl] = z;
        }
        return;
    }
    // epilogue: all 64 lanes active; wave covers 16 consecutive nodes
    const float* srow = (node < N_USERS)
        ? uemb + (size_t)node * EMB_DIM
        : iemb + (size_t)(node - N_USERS) * EMB_DIM;
    float4 a0 = ((const float4*)srow)[sl * 4 + 0];
    float4 a1 = ((const float4*)srow)[sl * 4 + 1];
    float4 a2 = ((const float4*)srow)[sl * 4 + 2];
    float4 a3 = ((const float4*)srow)[sl * 4 + 3];
    float v[16];
    v[0]  = dh * acc[0]  + a0.x; v[1]  = dh * acc[1]  + a0.y;
    v[2]  = dh * acc[2]  + a0.z; v[3]  = dh * acc[3]  + a0.w;
    v[4]  = dh * acc[4]  + a1.x; v[5]  = dh * acc[5]  + a1.y;
    v[6]  = dh * acc[6]  + a1.z; v[7]  = dh * acc[7]  + a1.w;
    v[8]  = dh * acc[8]  + a2.x; v[9]  = dh * acc[9]  + a2.y;
    v[10] = dh * acc[10] + a2.z; v[11] = dh * acc[11] + a2.w;
    v[12] = dh * acc[12] + a3.x; v[13] = dh * acc[13] + a3.y;
    v[14] = dh * acc[14] + a3.z; v[15] = dh * acc[15] + a3.w;
    uint4 ow;
    u32 w;
    w = __builtin_amdgcn_cvt_pk_fp8_f32(dh * v[0],  dh * v[1],  0, false);
    w = __builtin_amdgcn_cvt_pk_fp8_f32(dh * v[2],  dh * v[3],  w, true);  ow.x = w;
    w = __builtin_amdgcn_cvt_pk_fp8_f32(dh * v[4],  dh * v[5],  0, false);
    w = __builtin_amdgcn_cvt_pk_fp8_f32(dh * v[6],  dh * v[7],  w, true);  ow.y = w;
    w = __builtin_amdgcn_cvt_pk_fp8_f32(dh * v[8],  dh * v[9],  0, false);
    w = __builtin_amdgcn_cvt_pk_fp8_f32(dh * v[10], dh * v[11], w, true);  ow.z = w;
    w = __builtin_amdgcn_cvt_pk_fp8_f32(dh * v[12], dh * v[13], 0, false);
    w = __builtin_amdgcn_cvt_pk_fp8_f32(dh * v[14], dh * v[15], w, true);  ow.w = w;
    ((uint4*)(dst8 + (size_t)node * EMB_DIM))[sl] = ow;   // 1 kB/wave, coalesced
    if (flags[node]) {
        u16x8 o0, o1;
        o0.s0 = f2bf(v[0]);  o0.s1 = f2bf(v[1]);  o0.s2 = f2bf(v[2]);  o0.s3 = f2bf(v[3]);
        o0.s4 = f2bf(v[4]);  o0.s5 = f2bf(v[5]);  o0.s6 = f2bf(v[6]);  o0.s7 = f2bf(v[7]);
        o1.s0 = f2bf(v[8]);  o1.s1 = f2bf(v[9]);  o1.s2 = f2bf(v[10]); o1.s3 = f2bf(v[11]);
        o1.s4 = f2bf(v[12]); o1.s5 = f2bf(v[13]); o1.s6 = f2bf(v[14]); o1.s7 = f2bf(v[15]);
        ((u16x8*)(dstb + (size_t)node * EMB_DIM))[sl * 2]     = o0;
        ((u16x8*)(dstb + (size_t)node * EMB_DIM))[sl * 2 + 1] = o1;
    }
}

// ---------- scoring with fused on-the-fly layer-2 rows ----------
// The three segments (u, pos, neg) are gathered INTERLEAVED x2-unrolled:
// 6 independent row-fetches in flight per iteration instead of 1 serial.
// Pad indices (j >= lim[k]) read the zero dummy row at N_NODES -> +0.0 adds
// appended after each segment's real tail, preserving per-segment add order.
__global__ void k_score(const int* __restrict__ users, const int* __restrict__ pos,
                        const int* __restrict__ neg,
                        const float* __restrict__ uemb, const float* __restrict__ iemb,
                        const u16* __restrict__ emb1b, const u8* __restrict__ emb1s8,
                        const int2* __restrict__ sde, const int* __restrict__ et,
                        const float* __restrict__ dinv,
                        float* __restrict__ pmf, float* __restrict__ psq) {
    __shared__ float smf[4], ssq[4];
    int gid = blockIdx.x * blockDim.x + threadIdx.x;
    int b = gid >> 6;
    int d = gid & 63;
    int w = threadIdx.x >> 6;
    int u  = users[b];
    int pi = pos[b];
    int ni = neg[b];
    int nodes[3];
    nodes[0] = u; nodes[1] = N_USERS + pi; nodes[2] = N_USERS + ni;
    float pre[3];
    pre[0] = uemb[(size_t)u * EMB_DIM + d];
    pre[1] = iemb[(size_t)pi * EMB_DIM + d];
    pre[2] = iemb[(size_t)ni * EMB_DIM + d];
    int s0[3], ne[3], ets[3], lim[3];
    float dv[3];
    #pragma unroll
    for (int k = 0; k < 3; ++k) {
        int v = nodes[k];
        int2 se = sde[v];
        s0[k] = se.x; ne[k] = se.y;
        dv[k] = dinv[v];
        ets[k] = (d < ne[k]) ? et[se.x + d] : 0;
        lim[k] = ne[k] < 64 ? ne[k] : 64;
    }
    int lmax = max(lim[0], max(lim[1], lim[2]));
    float ac[3] = {0.f, 0.f, 0.f};
    for (int j = 0; j < lmax; j += 2) {        // 6 gathers in flight
        u32 by[6];
        #pragma unroll
        for (int k = 0; k < 3; ++k) {
            int t0 = (j     < lim[k]) ? __shfl(ets[k], j,     64) : N_NODES;
            int t1 = (j + 1 < lim[k]) ? __shfl(ets[k], j + 1, 64) : N_NODES;
            by[k * 2]     = emb1s8[(size_t)t0 * EMB_DIM + d];
            by[k * 2 + 1] = emb1s8[(size_t)t1 * EMB_DIM + d];
        }
        #pragma unroll
        for (int k = 0; k < 3; ++k) {
            ac[k] += __builtin_amdgcn_cvt_f32_fp8(by[k * 2],     0);
            ac[k] += __builtin_amdgcn_cvt_f32_fp8(by[k * 2 + 1], 0);
        }
    }
    float a[3];
    #pragma unroll
    for (int k = 0; k < 3; ++k) {
        float acx = ac[k];
        for (int i = s0[k] + 64; i < s0[k] + ne[k]; ++i) {   // rare deg>64 tail
            int t = et[i];
            u32 byte = emb1s8[(size_t)t * EMB_DIM + d];
            acx += __builtin_amdgcn_cvt_f32_fp8(byte, 0);
        }
        a[k] = pre[k] + 2.0f * bf2f(emb1b[(size_t)nodes[k] * EMB_DIM + d]) + dv[k] * acx;
    }
    float ps = a[0] * a[1];
    float ns = a[0] * a[2];
    float sq = pre[0] * pre[0] + pre[1] * pre[1] + pre[2] * pre[2];
    #pragma unroll
    for (int off2 = 32; off2 > 0; off2 >>= 1) {
        ps += __shfl_down(ps, off2, 64);
        ns += __shfl_down(ns, off2, 64);
        sq += __shfl_down(sq, off2, 64);
    }
    if (d == 0) {
        float x  = ns - ps;
        smf[w] = fmaxf(x, 0.0f) + log1pf(expf(-fabsf(x)));
        ssq[w] = sq;
    }
    __syncthreads();
    if (threadIdx.x == 0) {
        pmf[blockIdx.x] = smf[0] + smf[1] + smf[2] + smf[3];
        psq[blockIdx.x] = ssq[0] + ssq[1] + ssq[2] + ssq[3];
    }
}

// ---------- final reduction ----------
__global__ void k_final(const float* __restrict__ pmf, const float* __restrict__ psq,
                        float* __restrict__ out) {
    __shared__ float smf[4], ssq[4];
    int tid = threadIdx.x;
    float mf = 0.f, sq = 0.f;
    #pragma unroll
    for (int i = 0; i < SCORE_BLOCKS / 256; ++i) {
        mf += pmf[tid + i * 256];
        sq += psq[tid + i * 256];
    }
    #pragma unroll
    for (int off2 = 32; off2 > 0; off2 >>= 1) {
        mf += __shfl_down(mf, off2, 64);
        sq += __shfl_down(sq, off2, 64);
    }
    if ((tid & 63) == 0) { smf[tid >> 6] = mf; ssq[tid >> 6] = sq; }
    __syncthreads();
    if (tid == 0) {
        out[0] = (smf[0] + smf[1] + smf[2] + smf[3]) * (1.0f / BATCH);
        out[1] = EMB_REG * (ssq[0] + ssq[1] + ssq[2] + ssq[3]);
    }
}

extern "C" void kernel_launch(void* const* d_in, const int* in_sizes, int n_in,
                              void* d_out, int out_size, void* d_ws, size_t ws_size,
                              hipStream_t stream) {
    const float* uemb  = (const float*)d_in[0];
    const float* iemb  = (const float*)d_in[1];
    const int*   all_h = (const int*)d_in[2];
    const int*   all_t = (const int*)d_in[3];
    const int*   users = (const int*)d_in[4];
    const int*   pos   = (const int*)d_in[5];
    const int*   neg   = (const int*)d_in[6];
    float* out = (float*)d_out;

    // workspace layout (int units); flags+bcur contiguous for single memset.
    // emb1s8 sized 300,001 rows (dummy zero row at index N_NODES) -- emb1b
    // starts 16 ints later to avoid overlap with the dummy row.
    int*   ws     = (int*)d_ws;
    float* dinv   = (float*)ws;                  // 300,032 floats
    int2*  sde    = (int2*)(ws + 300032);        // 600,064 ints
    u8*    flags  = (u8*)(ws + 900096);          // 75,008 ints (300,032 B)
    int*   bcur   = ws + 975104;                 // 1024 ints (zero-init, relative)
    float* pmf    = (float*)(ws + 976128);       // 2048
    float* psq    = (float*)(ws + 978176);       // 2048
    int*   gp     = ws + 980224;                 // 586*7424 = 4,350,464 ints
    u8*    e0s8   = (u8*)(ws + 5330688);         // 300,001 rows x 64 B (incl dummy)
    u8*    emb1s8 = (u8*)(ws + 10130944);        // 300,001 rows x 64 B (incl dummy)
    u16*   emb1b  = (u16*)(ws + 14930960);       // 9.6M ints (38.4 MB)

    // one memset covers flags (300,032 B) + bcur (4,096 B)
    hipMemsetAsync(flags, 0, 304128, stream);

    // partition (+ folded mark + e0s8 dummy-row zero)
    kA <<<NBLK_A + NBLK_MARK, 256, 0, stream>>>(all_h, all_t, bcur, gp,
                                                users, pos, neg, flags, e0s8);
    kB <<<NBUCK, 256, 0, stream>>>(bcur, gp, sde, dinv, uemb, iemb, e0s8);

    // layer 1: emb1 = A*Q(dinv*e0) + e0  (16 nodes/wave, 16 rows/load-instr)
    k_spmm1<<<(N_NODES + 63) / 64, 256, 0, stream>>>(sde, gp, e0s8, uemb, iemb,
                                                     flags, emb1b, emb1s8);

    // scoring with interleaved 6-deep gathers
    k_score<<<SCORE_BLOCKS, 256, 0, stream>>>(users, pos, neg, uemb, iemb,
                                              emb1b, emb1s8, sde, gp, dinv, pmf, psq);
    k_final<<<1, 256, 0, stream>>>(pmf, psq, out);
}